// Round 15
// baseline (159.380 us; speedup 1.0000x reference)
//
#include <hip/hip_runtime.h>

typedef unsigned int u32;
typedef unsigned short u16;
typedef __attribute__((ext_vector_type(4))) float fx4;
typedef __attribute__((ext_vector_type(8))) short s16x8;
typedef __attribute__((ext_vector_type(4))) u32 u32x4;

#define DD 128
#define KK 1024

__device__ __forceinline__ u16 f2bf(float f) {
  u32 u = __float_as_uint(f);
  return (u16)((u + 0x7FFFu + ((u >> 16) & 1u)) >> 16);
}
__device__ __forceinline__ u32 umin32(u32 a, u32 b) { return a < b ? a : b; }

// packed bf16 RNE convert: bf16(lo) -> bits[15:0], bf16(hi) -> bits[31:16]
__device__ __forceinline__ u32 cvtpk(float lo, float hi) {
  u32 r;
  asm("v_cvt_pk_bf16_f32 %0, %1, %2" : "=v"(r) : "v"(lo), "v"(hi));
  return r;
}
// same, with free VOP3 neg modifiers on both inputs
__device__ __forceinline__ u32 cvtpkn(float lo, float hi) {
  u32 r;
  asm("v_cvt_pk_bf16_f32 %0, -%1, -%2" : "=v"(r) : "v"(lo), "v"(hi));
  return r;
}
__device__ __forceinline__ s16x8 as_s16x8(u32x4 v) {
  union { u32x4 u; s16x8 s; } x;
  x.u = v;
  return x.s;
}

// ---------------- prep: cbf fp32 -> bf16 (RTN, bit-identical to prior rounds),
// k-major cbt: [lvl(4)][ku(16)][col(1024)][8] u16 (1 MiB). 256 blocks x 64 thr,
// block = 16 codewords. Also zeroes the loss slot in d_out. (unchanged)
extern "C" __global__ __launch_bounds__(64) void rvq_prep(
    const float* __restrict__ cbf, u16* __restrict__ cbt,
    float* __restrict__ lossout) {
  if (blockIdx.x == 0 && threadIdx.x == 0) lossout[0] = 0.f;
  const int cl = threadIdx.x >> 2, dq = threadIdx.x & 3;
  const int cw = blockIdx.x * 16 + cl;
  const int lvl = cw >> 10, colg = cw & 1023;
  const float* src = cbf + (size_t)cw * DD + dq * 32;
  u32x4* dst = (u32x4*)cbt;
#pragma unroll
  for (int k8 = 0; k8 < 4; ++k8) {
    const fx4 a = *(const fx4*)(src + k8 * 8);
    const fx4 b = *(const fx4*)(src + k8 * 8 + 4);
    u32x4 pk;
    pk.x = (u32)f2bf(a[0]) | ((u32)f2bf(a[1]) << 16);
    pk.y = (u32)f2bf(a[2]) | ((u32)f2bf(a[3]) << 16);
    pk.z = (u32)f2bf(b[0]) | ((u32)f2bf(b[1]) << 16);
    pk.w = (u32)f2bf(b[2]) | ((u32)f2bf(b[3]) << 16);
    dst[((lvl * 16 + dq * 4 + k8) * 1024) + colg] = pk;  // 1 KB-coalesced across block
  }
}

// ---------------- main: 512 blocks x 256 thr; block = 64 rows x 1024 cols.
// CHAMPION r13 (72us: depth-3 + Xlds + setprio) + ONE hypothesis test:
// SPLIT-ACCUMULATOR MFMA chains. r13's residual wall: ~2580 cyc/KSTEP vs
// ~900 accounted; loads proven covered (r14: manual counted vmcnt = neutral),
// depth proven secondary (r4: 1->3 = +6.5%), TLP proven non-remedy (r7).
// Last un-probed serializer: dependent-MFMA latency — r13 runs 4 chains of
// 4 DEPENDENT MFMAs (interleave distance 4 insts ~78 cyc). Here: 8 chains
// of 2 (acP = 0.75+frag0+frag2, acQ = 0+frag1+frag3, key on acP+acQ),
// interleave distance 8 insts ~155 cyc.
// Register class: peak ~150 (afr 64 + buf 32 + acc 32 + run 16 + misc).
// (256,1) sets allocator budget 256 (no forced spill — r10 ran 172 clean);
// m69 occupancy steps at 64/128/256 => 129-256 regs still allows 2
// waves/SIMD = this grid's residency. Buffers at depth-1 (r4: costs ~6%).
// fp sum order changes ulp-level only; competing-codeword key gaps ~1e-4
// >> ulp 6e-8 — picks stable, absmax expected unchanged-or-negligible.
// Ledger: r1/2/6 bound-spill; r3 tile tail; r5/r8/r11 spill at 128-budget;
// r7 TLP null; r9 staging anomaly; r10 schedule regression at 172 regs;
// r13 setprio +10%; r14 counted-vmcnt neutral (drain theory refuted).
extern "C" __global__ __launch_bounds__(256, 1) void rvq_main(
    const float* __restrict__ x, const float* __restrict__ cbf,
    const u16* __restrict__ cbt, float* __restrict__ yout,
    float* __restrict__ lossacc) {
  __shared__ float Rlds[64][132];  // negated residual, single copy; +4 pad
  __shared__ float Xlds[64][132];  // raw x tile (final level: y = x + R)
  __shared__ u32 lmin[64][4];      // [row][wave]

  const int tid = threadIdx.x;
  const int wv = tid >> 6, lane = tid & 63;
  const int c = lane & 15, q = lane >> 4;
  const int rowbase = blockIdx.x * 64;
  const int rot = (int)((blockIdx.x >> 3) & 15);  // de-lockstep same-XCD L2 streams
  const s16x8* cbt16 = (const s16x8*)cbt;         // 16B units: [lvl][ku][col]

  s16x8 afr[4][4];  // A-frags: afr[t][s] -> rows t*16+c, k = s*32 + q*8 + j
#pragma unroll
  for (int t = 0; t < 4; ++t) {
    const float* xr = x + (size_t)(rowbase + t * 16 + c) * DD + q * 8;
#pragma unroll
    for (int s = 0; s < 4; ++s) {
      const fx4 a = *(const fx4*)(xr + s * 32);
      const fx4 b = *(const fx4*)(xr + s * 32 + 4);
      u32x4 af;
      af.x = cvtpkn(a[0], a[1]);
      af.y = cvtpkn(a[2], a[3]);
      af.z = cvtpkn(b[0], b[1]);
      af.w = cvtpkn(b[2], b[3]);
      afr[t][s] = as_s16x8(af);
      if (t == wv) {  // wave wv owns rows wv*16..wv*16+15 of Rlds AND Xlds
        fx4 na, nb;
#pragma unroll
        for (int j = 0; j < 4; ++j) { na[j] = -a[j]; nb[j] = -b[j]; }
        *(fx4*)&Rlds[t * 16 + c][s * 32 + q * 8] = na;
        *(fx4*)&Rlds[t * 16 + c][s * 32 + q * 8 + 4] = nb;
        *(fx4*)&Xlds[t * 16 + c][s * 32 + q * 8] = a;
        *(fx4*)&Xlds[t * 16 + c][s * 32 + q * 8 + 4] = b;
      }
    }
  }

  u32 run[4][4];
#pragma unroll
  for (int t = 0; t < 4; ++t)
#pragma unroll
    for (int r = 0; r < 4; ++r) run[t][r] = 0xFFFFFFFFu;

  float lsum = 0.f;

#pragma unroll 1
  for (int lvl = 0; lvl < 4; ++lvl) {
    const s16x8* cl = cbt16 + lvl * 16384 + q * 1024 + c;  // + s*4096 + colbase
    s16x8 brA[4], brB[4];
    {  // warm start: block rot into brA
      const int cb0 = rot * 64 + wv * 16;
#pragma unroll
      for (int s5 = 0; s5 < 4; ++s5) brA[s5] = cl[s5 * 4096 + cb0];
    }
    // acc = 0.75 - r.c  in (0.625, 0.875) [|r.c| <= ~0.04 here, wrap-safe to 0.125]
    // key = (bits(acP+acQ))<<10) + col - 2^31 : monotone, ties -> lowest col.
    // Split accumulators: acP[t] = 0.75 + frag0 + frag2; acQ[t] = 0 + frag1 +
    // frag3 — 8 independent dep-2 chains (emit order P0..P3,Q0..Q3,P0..):
    // inter-dependency distance 8 MFMAs (~155 cyc) vs r13's 4 (~78 cyc).
#define KSTEP(CUR, NXT, CT)                                                        \
  {                                                                                \
    if ((CT) < 15) {                                                               \
      const int cbn = ((((CT) + 1 + rot) & 15) * 64) + wv * 16;                    \
      _Pragma("unroll") for (int s5 = 0; s5 < 4; ++s5)                             \
          NXT[s5] = cl[s5 * 4096 + cbn];                                           \
    }                                                                              \
    const u32 kadd = (u32)(((((CT) + rot) & 15) * 64) + wv * 16 + c) - 0x80000000u;\
    fx4 aP0 = {0.75f, 0.75f, 0.75f, 0.75f};                                        \
    fx4 aP1 = aP0, aP2 = aP0, aP3 = aP0;                                           \
    fx4 aQ0 = {0.f, 0.f, 0.f, 0.f};                                                \
    fx4 aQ1 = aQ0, aQ2 = aQ0, aQ3 = aQ0;                                           \
    __builtin_amdgcn_s_setprio(1);                                                 \
    aP0 = __builtin_amdgcn_mfma_f32_16x16x32_bf16(afr[0][0], CUR[0], aP0, 0, 0, 0);\
    aP1 = __builtin_amdgcn_mfma_f32_16x16x32_bf16(afr[1][0], CUR[0], aP1, 0, 0, 0);\
    aP2 = __builtin_amdgcn_mfma_f32_16x16x32_bf16(afr[2][0], CUR[0], aP2, 0, 0, 0);\
    aP3 = __builtin_amdgcn_mfma_f32_16x16x32_bf16(afr[3][0], CUR[0], aP3, 0, 0, 0);\
    aQ0 = __builtin_amdgcn_mfma_f32_16x16x32_bf16(afr[0][1], CUR[1], aQ0, 0, 0, 0);\
    aQ1 = __builtin_amdgcn_mfma_f32_16x16x32_bf16(afr[1][1], CUR[1], aQ1, 0, 0, 0);\
    aQ2 = __builtin_amdgcn_mfma_f32_16x16x32_bf16(afr[2][1], CUR[1], aQ2, 0, 0, 0);\
    aQ3 = __builtin_amdgcn_mfma_f32_16x16x32_bf16(afr[3][1], CUR[1], aQ3, 0, 0, 0);\
    aP0 = __builtin_amdgcn_mfma_f32_16x16x32_bf16(afr[0][2], CUR[2], aP0, 0, 0, 0);\
    aP1 = __builtin_amdgcn_mfma_f32_16x16x32_bf16(afr[1][2], CUR[2], aP1, 0, 0, 0);\
    aP2 = __builtin_amdgcn_mfma_f32_16x16x32_bf16(afr[2][2], CUR[2], aP2, 0, 0, 0);\
    aP3 = __builtin_amdgcn_mfma_f32_16x16x32_bf16(afr[3][2], CUR[2], aP3, 0, 0, 0);\
    aQ0 = __builtin_amdgcn_mfma_f32_16x16x32_bf16(afr[0][3], CUR[3], aQ0, 0, 0, 0);\
    aQ1 = __builtin_amdgcn_mfma_f32_16x16x32_bf16(afr[1][3], CUR[3], aQ1, 0, 0, 0);\
    aQ2 = __builtin_amdgcn_mfma_f32_16x16x32_bf16(afr[2][3], CUR[3], aQ2, 0, 0, 0);\
    aQ3 = __builtin_amdgcn_mfma_f32_16x16x32_bf16(afr[3][3], CUR[3], aQ3, 0, 0, 0);\
    __builtin_amdgcn_s_setprio(0);                                                 \
    _Pragma("unroll") for (int r5 = 0; r5 < 4; ++r5) {                             \
      run[0][r5] = umin32(run[0][r5],                                              \
                          (__float_as_uint(aP0[r5] + aQ0[r5]) << 10) + kadd);      \
      run[1][r5] = umin32(run[1][r5],                                              \
                          (__float_as_uint(aP1[r5] + aQ1[r5]) << 10) + kadd);      \
      run[2][r5] = umin32(run[2][r5],                                              \
                          (__float_as_uint(aP2[r5] + aQ2[r5]) << 10) + kadd);      \
      run[3][r5] = umin32(run[3][r5],                                              \
                          (__float_as_uint(aP3[r5] + aQ3[r5]) << 10) + kadd);      \
    }                                                                              \
  }
    KSTEP(brA, brB, 0)  KSTEP(brB, brA, 1)  KSTEP(brA, brB, 2)  KSTEP(brB, brA, 3)
    KSTEP(brA, brB, 4)  KSTEP(brB, brA, 5)  KSTEP(brA, brB, 6)  KSTEP(brB, brA, 7)
    KSTEP(brA, brB, 8)  KSTEP(brB, brA, 9)  KSTEP(brA, brB, 10) KSTEP(brB, brA, 11)
    KSTEP(brA, brB, 12) KSTEP(brB, brA, 13) KSTEP(brA, brB, 14) KSTEP(brB, brA, 15)
#undef KSTEP

    // reduce over the 16 c-lanes (row lives on q*4+r within tile t)
#pragma unroll
    for (int m = 1; m < 16; m <<= 1)
#pragma unroll
      for (int t = 0; t < 4; ++t)
#pragma unroll
        for (int r = 0; r < 4; ++r)
          run[t][r] = umin32(run[t][r], (u32)__shfl_xor((int)run[t][r], m, 64));
    if (c == 0) {
#pragma unroll
      for (int t = 0; t < 4; ++t)
#pragma unroll
        for (int r = 0; r < 4; ++r)
          lmin[t * 16 + q * 4 + r][wv] = run[t][r];
    }
    __syncthreads();  // lmin complete across the 4 waves

    // update own rows: row = wv*16 + c, dims q*32..q*32+31 (exact fp32 codebook)
    const int row = wv * 16 + c;
    const u32x4 p = *(const u32x4*)&lmin[row][0];
    const u32 pm = umin32(umin32(p.x, p.y), umin32(p.z, p.w));
    const int col = (int)(pm & 1023u);
    const float* qp = cbf + ((size_t)lvl * KK + col) * DD + q * 32;
    float* Rr = &Rlds[row][q * 32];
    if (lvl < 3) {
#pragma unroll
      for (int k4 = 0; k4 < 8; ++k4) {
        fx4 rv = *(const fx4*)(Rr + k4 * 4);
        const fx4 qv = *(const fx4*)(qp + k4 * 4);
#pragma unroll
        for (int j = 0; j < 4; ++j) { rv[j] += qv[j]; lsum = fmaf(rv[j], rv[j], lsum); }
        *(fx4*)(Rr + k4 * 4) = rv;
      }
      __syncthreads();  // new residual visible; also orders lmin reads vs next level
      // rebuild all 64 rows' A-frags from Rlds; reset keys
#pragma unroll
      for (int t = 0; t < 4; ++t)
#pragma unroll
        for (int s = 0; s < 4; ++s) {
          const fx4 r0 = *(const fx4*)&Rlds[t * 16 + c][s * 32 + q * 8];
          const fx4 r1 = *(const fx4*)&Rlds[t * 16 + c][s * 32 + q * 8 + 4];
          u32x4 af;
          af.x = cvtpk(r0[0], r0[1]);
          af.y = cvtpk(r0[2], r0[3]);
          af.z = cvtpk(r1[0], r1[1]);
          af.w = cvtpk(r1[2], r1[3]);
          afr[t][s] = as_s16x8(af);
        }
#pragma unroll
      for (int t = 0; t < 4; ++t)
#pragma unroll
        for (int r = 0; r < 4; ++r) run[t][r] = 0xFFFFFFFFu;
    } else {  // final level: y = x + R_final (forward value = q_sum), x from Xlds
      const size_t gb = (size_t)(rowbase + row) * DD + q * 32;
      const float* Xr = &Xlds[row][q * 32];
#pragma unroll
      for (int k4 = 0; k4 < 8; ++k4) {
        fx4 rv = *(const fx4*)(Rr + k4 * 4);
        const fx4 qv = *(const fx4*)(qp + k4 * 4);
        const fx4 xv = *(const fx4*)(Xr + k4 * 4);
        fx4 yv;
#pragma unroll
        for (int j = 0; j < 4; ++j) {
          rv[j] += qv[j];
          lsum = fmaf(rv[j], rv[j], lsum);
          yv[j] = xv[j] + rv[j];
        }
        *(fx4*)(yout + gb + k4 * 4) = yv;
      }
    }
  }

#pragma unroll
  for (int m = 32; m >= 1; m >>= 1) lsum += __shfl_xor(lsum, m, 64);
  if (lane == 0) atomicAdd(lossacc, lsum * (1.25f / 4194304.f));  // 1.25/(N*D)
}

extern "C" void kernel_launch(void* const* d_in, const int* in_sizes, int n_in,
                              void* d_out, int out_size, void* d_ws, size_t ws_size,
                              hipStream_t stream) {
  const float* x = (const float*)d_in[0];     // [32768,128]
  const float* cbf = (const float*)d_in[1];   // [4,1024,128]
  float* y = (float*)d_out;
  float* lossout = y + (out_size - 1);
  u16* cbt = (u16*)d_ws;                      // 1 MiB k-major bf16 codebook

  rvq_prep<<<256, 64, 0, stream>>>(cbf, cbt, lossout);
  rvq_main<<<512, 256, 0, stream>>>(x, cbf, cbt, y, lossout);
}